// Round 14
// baseline (72.203 us; speedup 1.0000x reference)
//
#include <hip/hip_runtime.h>
#include <math.h>

// Problem constants (batch=1024, dim_z=32, n_samples=32, agg_size=256)
#define B    1024
#define D    32
#define NS   32
#define AGG  256
#define NC   (B / AGG)      // 4 chunks
#define M    (AGG * NS)     // 8192 samples per chunk
#define NJB  8              // eval j-blocks per (c,k)
#define JB   (M / NJB)      // 1024 samples per block
#define TJ   (JB / 256)     // 4 samples per thread
#define NBLK (NC * D * NJB) // 1024 eval blocks

// Table: L(z)=log2 S(z) on z in [-64,64], h=1/16, 2048 nodes/(c,k).
// Same h as r11 (absmax 0.0); wider range removes the exact-fallback call.
#define TN     2048
#define ZMIN   (-64.0f)
#define INVH   16.0f
#define HH     0.0625f
#define ZCLAMP 63.5f

// ws: [0] uint counter | @256 float partial[1024] (4KB) | @8192 float2 table (2MB)
#define WS_TABLE 8192
#define WS_NEED  (8192 + 128 * TN * 8)

#define LOG2E 1.4426950408889634f
#define LN2   0.6931471805599453f

// Fused params+table. 1024 blocks = 128 ck x 8 segments of 256 nodes.
// Phase A: per-block LDS params (no global param table -> no K$ thrash).
// Phase B: 1 node/thread, 256 comps with WAVE-UNIFORM CULLING: a comp >18sd
// from the wave's node window underflows to exactly 0.0f -> skipping is
// bit-exact. Typical cull ~2/3 of all (comp,wave) pairs; far-tail windows
// cull ~everything.
__global__ __launch_bounds__(256) void kparamtab(const float* __restrict__ mean,
                                                 const float* __restrict__ logvar,
                                                 float2* __restrict__ table,
                                                 unsigned* __restrict__ counter)
{
    const int bid = blockIdx.x;
    const int ck  = bid >> 3;
    const int seg = bid & 7;
    const int c   = ck >> 5;
    const int k   = ck & (D - 1);
    const int t   = threadIdx.x;
    if (bid == 0 && t == 0) counter[0] = 0u;   // reset keval's last-block counter

    __shared__ float4 pABC[AGG];   // {A, B, C, 0}: arg(z)=A z^2+B z+C (log2 units)
    __shared__ float2 pms[AGG];    // {mu, 18*sd+1}
    {
        const int row  = (c << 8) + t;
        const float mu = mean[row * D + k];
        const float lv = logvar[row * D + k];
        const float ev = __builtin_amdgcn_exp2f(-lv * LOG2E);   // exp(-lv)
        pABC[t] = make_float4(-0.5f * LOG2E * ev,
                              LOG2E * mu * ev,
                              -0.5f * LOG2E * fmaf(mu * mu, ev, lv), 0.f);
        const float sd = __builtin_amdgcn_exp2f(0.5f * LOG2E * lv);
        pms[t] = make_float2(mu, fmaf(18.f, sd, 1.f));
    }
    __syncthreads();

    const int g   = (seg << 8) + t;                 // node 0..2047
    const float z = fmaf((float)g, HH, ZMIN);
    const int gw0 = (seg << 8) + (t & 192);         // wave's 64-node base
    const float zlo = fmaf((float)gw0, HH, ZMIN);
    const float zhi = zlo + 63.f * HH;

    float acc = 0.f, dacc = 0.f;
    for (int i = 0; i < AGG; ++i) {
        const float2 ms = pms[i];
        const float dpos = fmaxf(fmaxf(zlo - ms.x, ms.x - zhi), 0.f);
        if (dpos < ms.y) {                          // uniform across wave -> execz skip
            const float4 p = pABC[i];
            const float ap = fmaf(p.x, z, p.y);     // A z + B
            const float w  = __builtin_amdgcn_exp2f(fmaf(ap, z, p.z));
            acc += w;
            dacc = fmaf(w, fmaf(2.f, ap, -p.y), dacc);   // arg' = 2Az+B
        }
    }
    const float ag = fmaxf(acc, 1e-30f);
    table[(ck << 11) | g] =
        make_float2(__builtin_amdgcn_logf(ag),
                    dacc * __builtin_amdgcn_rcpf(ag) * HH);
}

// Eval: cubic Hermite on the staged table. NO function calls, no fallback.
__global__ __launch_bounds__(256) void keval(const float* __restrict__ eps,
                                             const float* __restrict__ mean,
                                             const float* __restrict__ logvar,
                                             const float2* __restrict__ table,
                                             float* __restrict__ partial,
                                             unsigned* __restrict__ counter,
                                             float* __restrict__ out)
{
    const int bid = blockIdx.x;
    const int ck  = bid >> 3;                 // c*D + k
    const int q   = bid & 7;
    const int c   = ck >> 5;
    const int k   = ck & (D - 1);
    const int j0  = q << 10;
    const int t   = threadIdx.x;

    // eps gathers first (latency hides under staging)
    float e[TJ];
#pragma unroll
    for (int u = 0; u < TJ; ++u)
        e[u] = eps[(size_t)((c << 13) + j0 + t + (u << 8)) * D + k];

    // row params for this block's 32 rows
    __shared__ float2 rowp[32];
    if (t < 32) {
        const int row  = (c << 8) + (q << 5) + t;
        const float mu = mean[row * D + k];
        const float lv = logvar[row * D + k];
        rowp[t] = make_float2(mu, __builtin_amdgcn_exp2f(0.5f * LOG2E * lv));
    }

    // stage table: 2048 float2 = 16KB, coalesced
    __shared__ float2 tab[TN];
    const float2* __restrict__ gt = table + (ck << 11);
#pragma unroll
    for (int p = 0; p < 8; ++p)
        tab[t + (p << 8)] = gt[t + (p << 8)];
    __syncthreads();

    float r = 0.f;
#pragma unroll
    for (int u = 0; u < TJ; ++u) {
        const float2 ms = rowp[(t >> 5) + (u << 3)];
        const float z  = fmaf(e[u], ms.y, ms.x);
        const float zc = fminf(fmaxf(z, -ZCLAMP), ZCLAMP);
        const float x  = fmaf(zc, INVH, 1024.0f);     // (zc - ZMIN)*INVH
        const float fg = floorf(x);
        const float f  = x - fg;
        const int  ig  = (int)fg;                     // in [8, 2040]
        const float2 n0 = tab[ig];
        const float2 n1 = tab[ig + 1];
        const float dl  = n1.x - n0.x;
        const float c2  = 3.f * dl - 2.f * n0.y - n1.y;
        const float c3  = n0.y + n1.y - 2.f * dl;
        const float L   = fmaf(f, fmaf(f, fmaf(f, c3, c2), n0.y), n0.x);
        r += fmaf(LN2, L, 0.5f * z * z);
    }

    // deterministic block reduction
    for (int off = 32; off > 0; off >>= 1) r += __shfl_down(r, off, 64);
    __shared__ float wsum[4];
    if ((t & 63) == 0) wsum[t >> 6] = r;
    __syncthreads();

    __shared__ int isLast;
    if (t == 0) {
        partial[bid] = (wsum[0] + wsum[1]) + (wsum[2] + wsum[3]);
        __threadfence();
        const unsigned old = atomicAdd(counter, 1u);
        isLast = (old == (unsigned)(NBLK - 1));
    }
    __syncthreads();
    if (isLast) {
        __threadfence();
        double s = 0.0;
#pragma unroll
        for (int i = 0; i < NBLK / 256; ++i) s += (double)partial[i * 256 + t];
        __shared__ double sd2[256];
        sd2[t] = s;
        __syncthreads();
        for (int off = 128; off > 0; off >>= 1) {
            if (t < off) sd2[t] += sd2[t + off];
            __syncthreads();
        }
        if (t == 0)
            out[0] = (float)(sd2[0] * (1.0 / (double)(NC * M))
                             - (double)D * 5.545177444479562);   // - D*ln(256)
    }
}

// ---- fallback path (ws too small for the table; never expected) ----
__global__ void kzero(unsigned* __restrict__ counter) { counter[0] = 0u; }

__global__ __launch_bounds__(256) void kfb(const float* __restrict__ eps,
                                           const float* __restrict__ mean,
                                           const float* __restrict__ logvar,
                                           float* __restrict__ partial,
                                           unsigned* __restrict__ counter,
                                           float* __restrict__ out)
{
    const int bid = blockIdx.x;
    const int ck  = bid >> 3;
    const int q   = bid & 7;
    const int c   = ck >> 5;
    const int k   = ck & (D - 1);
    const int j0  = q << 10;
    const int t   = threadIdx.x;

    __shared__ float4 prm[AGG];
    {
        const int row  = (c << 8) + t;
        const float mu = mean[row * D + k];
        const float lv = logvar[row * D + k];
        const float ev = __builtin_amdgcn_exp2f(-lv * LOG2E);
        prm[t] = make_float4(-0.5f * LOG2E * ev, LOG2E * mu * ev,
                             -0.5f * LOG2E * fmaf(mu * mu, ev, lv),
                             __builtin_amdgcn_exp2f(0.5f * LOG2E * lv));
    }
    __syncthreads();

    float zv[TJ], acc[TJ];
#pragma unroll
    for (int u = 0; u < TJ; ++u) {
        const int j    = j0 + t + (u << 8);
        const float4 p = prm[j >> 5];
        const float mu = -0.5f * p.y * __builtin_amdgcn_rcpf(p.x);
        zv[u]  = fmaf(eps[(size_t)((c << 13) + j) * D + k], p.w, mu);
        acc[u] = 0.f;
    }
#pragma unroll 4
    for (int i = 0; i < AGG; ++i) {
        const float4 p = prm[i];
#pragma unroll
        for (int u = 0; u < TJ; ++u)
            acc[u] += __builtin_amdgcn_exp2f(fmaf(fmaf(p.x, zv[u], p.y), zv[u], p.z));
    }
    float r = 0.f;
#pragma unroll
    for (int u = 0; u < TJ; ++u)
        r += LN2 * __builtin_amdgcn_logf(acc[u]) + 0.5f * zv[u] * zv[u];

    for (int off = 32; off > 0; off >>= 1) r += __shfl_down(r, off, 64);
    __shared__ float wsum[4];
    if ((t & 63) == 0) wsum[t >> 6] = r;
    __syncthreads();
    __shared__ int isLast;
    if (t == 0) {
        partial[bid] = (wsum[0] + wsum[1]) + (wsum[2] + wsum[3]);
        __threadfence();
        const unsigned old = atomicAdd(counter, 1u);
        isLast = (old == (unsigned)(NBLK - 1));
    }
    __syncthreads();
    if (isLast) {
        __threadfence();
        double s = 0.0;
#pragma unroll
        for (int i = 0; i < NBLK / 256; ++i) s += (double)partial[i * 256 + t];
        __shared__ double sd2[256];
        sd2[t] = s;
        __syncthreads();
        for (int off = 128; off > 0; off >>= 1) {
            if (t < off) sd2[t] += sd2[t + off];
            __syncthreads();
        }
        if (t == 0)
            out[0] = (float)(sd2[0] * (1.0 / (double)(NC * M))
                             - (double)D * 5.545177444479562);
    }
}

extern "C" void kernel_launch(void* const* d_in, const int* in_sizes, int n_in,
                              void* d_out, int out_size, void* d_ws, size_t ws_size,
                              hipStream_t stream)
{
    const float* mean   = (const float*)d_in[0];
    const float* logvar = (const float*)d_in[1];
    const float* eps    = (const float*)d_in[2];
    float* out = (float*)d_out;

    unsigned* counter = (unsigned*)d_ws;
    float*    partial = (float*)((char*)d_ws + 256);
    float2*   table   = (float2*)((char*)d_ws + WS_TABLE);

    if (ws_size >= (size_t)WS_NEED) {
        kparamtab<<<NC * D * 8, 256, 0, stream>>>(mean, logvar, table, counter);
        keval<<<NBLK, 256, 0, stream>>>(eps, mean, logvar, table, partial, counter, out);
    } else {
        kzero<<<1, 64, 0, stream>>>(counter);
        kfb<<<NBLK, 256, 0, stream>>>(eps, mean, logvar, partial, counter, out);
    }
}

// Round 15
// 48.361 us; speedup vs baseline: 1.4930x; 1.4930x over previous
//
#include <hip/hip_runtime.h>
#include <math.h>

// Problem constants (batch=1024, dim_z=32, n_samples=32, agg_size=256)
#define B    1024
#define D    32
#define NS   32
#define AGG  256
#define NC   (B / AGG)      // 4 chunks
#define M    (AGG * NS)     // 8192 samples per chunk
#define NJB  8              // eval j-blocks per (c,k)
#define JB   (M / NJB)      // 1024 samples per block
#define TJ   4              // one float4 of epsT per thread
#define NBLK (NC * D * NJB) // 1024 eval blocks

// Table: L(z)=log2 S(z) on z in [-32,32], h=1/16, 1024 nodes/(c,k)  (r11/r13 h: absmax 0.0)
#define TN     1024
#define ZMIN   (-32.0f)
#define INVH   16.0f
#define HH     0.0625f
#define ZCLAMP 31.9f

// ws: [0] counter | @256 partial[1024] (4KB) | @8192 params (512KB)
//     | @532480 table (1MB) | @1581056 epsT (4MB)
#define WS_PARTIAL 256
#define WS_PARAMS  8192
#define WS_TABLE   532480
#define WS_EPST    1581056
#define WS_NEED    5775360

#define LOG2E 1.4426950408889634f
#define LN2   0.6931471805599453f

// params[(ck<<8)|i] = {A,B,C,sd}: arg(z)=A z^2+B z+C (log2 units), sd=exp(lv/2)
__global__ __launch_bounds__(256) void ksetup(const float* __restrict__ mean,
                                              const float* __restrict__ logvar,
                                              float4* __restrict__ params,
                                              unsigned* __restrict__ counter)
{
    const int tid = blockIdx.x * 256 + threadIdx.x;   // over B*D, k fastest
    if (tid == 0) counter[0] = 0u;
    const int row = tid >> 5;
    const int k   = tid & (D - 1);
    const int c   = row >> 8;
    const int i   = row & (AGG - 1);
    const float mu = mean[tid];
    const float lv = logvar[tid];
    const float ev = __builtin_amdgcn_exp2f(-lv * LOG2E);   // exp(-lv); lv~N(0,1): safe
    params[(((c << 5) | k) << 8) | i] =
        make_float4(-0.5f * LOG2E * ev,
                    LOG2E * mu * ev,
                    -0.5f * LOG2E * fmaf(mu * mu, ev, lv),
                    __builtin_amdgcn_exp2f(0.5f * LOG2E * lv));
}

// Transpose eps[c][j][k] -> epsT[ck][j] via 32x33 LDS tile; both sides coalesced.
// Removes the 128B-lane-stride gather (r14: 39us @ 2% VALU = MSHR-latency-bound).
__global__ __launch_bounds__(256) void ktrans(const float* __restrict__ eps,
                                              float* __restrict__ epsT)
{
    const int bid = blockIdx.x;            // 4 * 256 blocks
    const int c   = bid >> 8;
    const int j0t = (bid & 255) << 5;      // 32-sample tile
    const int t   = threadIdx.x;
    const int x   = t & 31;
    const int y0  = t >> 5;
    __shared__ float tile[32][33];
#pragma unroll
    for (int p = 0; p < 4; ++p) {
        const int r = (p << 3) + y0;
        tile[r][x] = eps[((size_t)c * M + j0t + r) * D + x];
    }
    __syncthreads();
#pragma unroll
    for (int p = 0; p < 4; ++p) {
        const int kk = (p << 3) + y0;
        epsT[(((size_t)c * D + kk) << 13) + j0t + x] = tile[x][kk];
    }
}

// Table build: 2048 blocks = 128ck x 16 segments of 64 nodes.
// Params staged in LDS (4KB coalesced once; no global/scalar access in the loop).
// Each of the 4 waves sums a 64-comp quarter for all 64 nodes (LDS broadcast reads),
// fixed-order LDS combine -> deterministic. 8 blocks/CU = 8 waves/SIMD of TLP.
__global__ __launch_bounds__(256) void ktable(const float4* __restrict__ params,
                                              float2* __restrict__ table)
{
    const int bid  = blockIdx.x;
    const int ck   = bid >> 4;
    const int g0   = (bid & 15) << 6;                // node base
    const int t    = threadIdx.x;
    const int lane = t & 63;
    const int wv   = t >> 6;                         // comp quarter

    __shared__ float4 ps[AGG];
    ps[t] = params[(ck << 8) | t];
    __syncthreads();

    const float z = fmaf((float)(g0 + lane), HH, ZMIN);
    float acc = 0.f, dacc = 0.f;
#pragma unroll 16
    for (int i = 0; i < 64; ++i) {
        const float4 p = ps[(wv << 6) + i];          // wave-uniform -> LDS broadcast
        const float ap = fmaf(p.x, z, p.y);          // A z + B
        const float w  = __builtin_amdgcn_exp2f(fmaf(ap, z, p.z));
        acc += w;
        dacc = fmaf(w, fmaf(2.f, ap, -p.y), dacc);   // arg' = 2Az + B
    }
    __shared__ float2 part[256];
    part[t] = make_float2(acc, dacc);
    __syncthreads();
    if (t < 64) {
        const float2 p0 = part[t];
        const float2 p1 = part[t + 64];
        const float2 p2 = part[t + 128];
        const float2 p3 = part[t + 192];
        const float a  = (p0.x + p1.x) + (p2.x + p3.x);
        const float d  = (p0.y + p1.y) + (p2.y + p3.y);
        const float ag = fmaxf(a, 1e-30f);           // unused far nodes only
        table[(ck << 10) | (g0 + t)] =
            make_float2(__builtin_amdgcn_logf(ag),
                        d * __builtin_amdgcn_rcpf(ag) * HH);
    }
}

// Eval: coalesced epsT float4 + cubic Hermite on LDS table. No calls, no fallback.
__global__ __launch_bounds__(256) void keval(const float* __restrict__ epsT,
                                             const float* __restrict__ mean,
                                             const float* __restrict__ logvar,
                                             const float2* __restrict__ table,
                                             float* __restrict__ partial,
                                             unsigned* __restrict__ counter,
                                             float* __restrict__ out)
{
    const int bid = blockIdx.x;
    const int ck  = bid >> 3;                 // c*D + k
    const int q   = bid & 7;
    const int c   = ck >> 5;
    const int k   = ck & (D - 1);
    const int j0  = q << 10;
    const int t   = threadIdx.x;

    // Coalesced: thread t owns samples j = j0 + 4t .. 4t+3 (one 16B load).
    const float4 e4 = *(const float4*)(epsT + ((size_t)ck << 13) + j0 + (t << 2));
    const float e[TJ] = {e4.x, e4.y, e4.z, e4.w};

    // Row params for this block's 32 rows (tiny gather, overlapped with staging).
    __shared__ float2 rowp[32];
    if (t < 32) {
        const int row  = (c << 8) + (q << 5) + t;
        rowp[t] = make_float2(mean[row * D + k],
                              __builtin_amdgcn_exp2f(0.5f * LOG2E * logvar[row * D + k]));
    }

    // Stage table: 1024 float2 = 8KB, coalesced.
    __shared__ float2 tab[TN];
    const float2* __restrict__ gt = table + (ck << 10);
#pragma unroll
    for (int p = 0; p < 4; ++p)
        tab[t + (p << 8)] = gt[t + (p << 8)];
    __syncthreads();

    const float2 ms = rowp[t >> 3];           // all 4 samples share one row
    float r = 0.f;
#pragma unroll
    for (int u = 0; u < TJ; ++u) {
        const float z  = fmaf(e[u], ms.y, ms.x);
        const float zc = fminf(fmaxf(z, -ZCLAMP), ZCLAMP);
        const float x  = fmaf(zc, INVH, 512.0f);      // (zc-ZMIN)*INVH
        const float fg = floorf(x);
        const float f  = x - fg;
        const int  ig  = (int)fg;                     // in [1,1022]
        const float2 n0 = tab[ig];
        const float2 n1 = tab[ig + 1];
        const float dl  = n1.x - n0.x;
        const float c2  = 3.f * dl - 2.f * n0.y - n1.y;
        const float c3  = n0.y + n1.y - 2.f * dl;
        const float L   = fmaf(f, fmaf(f, fmaf(f, c3, c2), n0.y), n0.x);
        r += fmaf(LN2, L, 0.5f * z * z);
    }

    // deterministic block reduction
    for (int off = 32; off > 0; off >>= 1) r += __shfl_down(r, off, 64);
    __shared__ float wsum[4];
    if ((t & 63) == 0) wsum[t >> 6] = r;
    __syncthreads();

    __shared__ int isLast;
    if (t == 0) {
        partial[bid] = (wsum[0] + wsum[1]) + (wsum[2] + wsum[3]);
        __threadfence();
        const unsigned old = atomicAdd(counter, 1u);
        isLast = (old == (unsigned)(NBLK - 1));
    }
    __syncthreads();
    if (isLast) {
        __threadfence();
        double s = 0.0;
#pragma unroll
        for (int i = 0; i < NBLK / 256; ++i) s += (double)partial[i * 256 + t];
        __shared__ double sd2[256];
        sd2[t] = s;
        __syncthreads();
        for (int off = 128; off > 0; off >>= 1) {
            if (t < off) sd2[t] += sd2[t + off];
            __syncthreads();
        }
        if (t == 0)
            out[0] = (float)(sd2[0] * (1.0 / (double)(NC * M))
                             - (double)D * 5.545177444479562);   // - D*ln(256)
    }
}

// ---- fallback (ws too small; not expected) ----
__global__ void kzero(unsigned* __restrict__ counter) { counter[0] = 0u; }

__global__ __launch_bounds__(256) void kfb(const float* __restrict__ eps,
                                           const float* __restrict__ mean,
                                           const float* __restrict__ logvar,
                                           float* __restrict__ partial,
                                           unsigned* __restrict__ counter,
                                           float* __restrict__ out)
{
    const int bid = blockIdx.x;
    const int ck  = bid >> 3;
    const int q   = bid & 7;
    const int c   = ck >> 5;
    const int k   = ck & (D - 1);
    const int j0  = q << 10;
    const int t   = threadIdx.x;

    __shared__ float4 prm[AGG];
    {
        const int row  = (c << 8) + t;
        const float mu = mean[row * D + k];
        const float lv = logvar[row * D + k];
        const float ev = __builtin_amdgcn_exp2f(-lv * LOG2E);
        prm[t] = make_float4(-0.5f * LOG2E * ev, LOG2E * mu * ev,
                             -0.5f * LOG2E * fmaf(mu * mu, ev, lv),
                             __builtin_amdgcn_exp2f(0.5f * LOG2E * lv));
    }
    __syncthreads();

    float zv[TJ], acc[TJ];
#pragma unroll
    for (int u = 0; u < TJ; ++u) {
        const int j    = j0 + t + (u << 8);
        const float4 p = prm[j >> 5];
        const float mu = -0.5f * p.y * __builtin_amdgcn_rcpf(p.x);
        zv[u]  = fmaf(eps[(size_t)((c << 13) + j) * D + k], p.w, mu);
        acc[u] = 0.f;
    }
#pragma unroll 4
    for (int i = 0; i < AGG; ++i) {
        const float4 p = prm[i];
#pragma unroll
        for (int u = 0; u < TJ; ++u)
            acc[u] += __builtin_amdgcn_exp2f(fmaf(fmaf(p.x, zv[u], p.y), zv[u], p.z));
    }
    float r = 0.f;
#pragma unroll
    for (int u = 0; u < TJ; ++u)
        r += LN2 * __builtin_amdgcn_logf(acc[u]) + 0.5f * zv[u] * zv[u];

    for (int off = 32; off > 0; off >>= 1) r += __shfl_down(r, off, 64);
    __shared__ float wsum[4];
    if ((t & 63) == 0) wsum[t >> 6] = r;
    __syncthreads();
    __shared__ int isLast;
    if (t == 0) {
        partial[bid] = (wsum[0] + wsum[1]) + (wsum[2] + wsum[3]);
        __threadfence();
        const unsigned old = atomicAdd(counter, 1u);
        isLast = (old == (unsigned)(NBLK - 1));
    }
    __syncthreads();
    if (isLast) {
        __threadfence();
        double s = 0.0;
#pragma unroll
        for (int i = 0; i < NBLK / 256; ++i) s += (double)partial[i * 256 + t];
        __shared__ double sd2[256];
        sd2[t] = s;
        __syncthreads();
        for (int off = 128; off > 0; off >>= 1) {
            if (t < off) sd2[t] += sd2[t + off];
            __syncthreads();
        }
        if (t == 0)
            out[0] = (float)(sd2[0] * (1.0 / (double)(NC * M))
                             - (double)D * 5.545177444479562);
    }
}

extern "C" void kernel_launch(void* const* d_in, const int* in_sizes, int n_in,
                              void* d_out, int out_size, void* d_ws, size_t ws_size,
                              hipStream_t stream)
{
    const float* mean   = (const float*)d_in[0];
    const float* logvar = (const float*)d_in[1];
    const float* eps    = (const float*)d_in[2];
    float* out = (float*)d_out;

    unsigned* counter = (unsigned*)d_ws;
    float*    partial = (float*)((char*)d_ws + WS_PARTIAL);
    float4*   params  = (float4*)((char*)d_ws + WS_PARAMS);
    float2*   table   = (float2*)((char*)d_ws + WS_TABLE);
    float*    epsT    = (float*)((char*)d_ws + WS_EPST);

    if (ws_size >= (size_t)WS_NEED) {
        ksetup<<<(B * D) / 256, 256, 0, stream>>>(mean, logvar, params, counter);
        ktrans<<<NC * 256, 256, 0, stream>>>(eps, epsT);
        ktable<<<NC * D * 16, 256, 0, stream>>>(params, table);
        keval<<<NBLK, 256, 0, stream>>>(epsT, mean, logvar, table, partial, counter, out);
    } else {
        kzero<<<1, 64, 0, stream>>>(counter);
        kfb<<<NBLK, 256, 0, stream>>>(eps, mean, logvar, partial, counter, out);
    }
}

// Round 16
// 42.989 us; speedup vs baseline: 1.6796x; 1.1250x over previous
//
#include <hip/hip_runtime.h>
#include <math.h>

// Problem constants (batch=1024, dim_z=32, n_samples=32, agg_size=256)
#define B    1024
#define D    32
#define NS   32
#define AGG  256
#define NC   4
#define M    8192            // samples per chunk
#define NEV  1024            // eval blocks (262144 threads x 4 terms = 1M terms)

// Table: L(z)=log2 S(z) on z in [-32,32], h=1/16, 1024 nodes/(c,k)  (absmax 0.0 at this h)
#define TN     1024
#define ZMIN   (-32.0f)
#define INVH   16.0f
#define HH     0.0625f
#define ZCLAMP 31.9f

// ws: [0] counter | @256 partial[1024] 4KB | @8192 params 512KB
//     | @532480 msd 256KB | @794624 table 1MB
#define WS_PARTIAL 256
#define WS_PARAMS  8192
#define WS_MSD     532480
#define WS_TABLE   794624
#define WS_NEED    (794624 + 128 * TN * 8)

#define LOG2E 1.4426950408889634f
#define LN2   0.6931471805599453f

// params[(ck<<8)|i] = {A,B,C,0}: arg(z)=A z^2+B z+C (log2 units)
// msd[row*D+k] = {mu, sd}
__global__ __launch_bounds__(256) void ksetup(const float* __restrict__ mean,
                                              const float* __restrict__ logvar,
                                              float4* __restrict__ params,
                                              float2* __restrict__ msd,
                                              unsigned* __restrict__ counter)
{
    const int tid = blockIdx.x * 256 + threadIdx.x;   // over B*D, k fastest
    if (tid == 0) counter[0] = 0u;
    const int row = tid >> 5;
    const int k   = tid & (D - 1);
    const int c   = row >> 8;
    const int i   = row & (AGG - 1);
    const float mu = mean[tid];
    const float lv = logvar[tid];
    const float ev = __builtin_amdgcn_exp2f(-lv * LOG2E);   // exp(-lv); lv~N(0,1): safe
    params[(((c << 5) | k) << 8) | i] =
        make_float4(-0.5f * LOG2E * ev,
                    LOG2E * mu * ev,
                    -0.5f * LOG2E * fmaf(mu * mu, ev, lv), 0.f);
    msd[tid] = make_float2(mu, __builtin_amdgcn_exp2f(0.5f * LOG2E * lv));
}

// ktable: r15 VERBATIM (control arm of the A/B).
// 2048 blocks = 128ck x 16 segments of 64 nodes; params staged in LDS;
// each wave sums a 64-comp quarter; fixed-order LDS combine.
__global__ __launch_bounds__(256) void ktable(const float4* __restrict__ params,
                                              float2* __restrict__ table)
{
    const int bid  = blockIdx.x;
    const int ck   = bid >> 4;
    const int g0   = (bid & 15) << 6;
    const int t    = threadIdx.x;
    const int lane = t & 63;
    const int wv   = t >> 6;

    __shared__ float4 ps[AGG];
    ps[t] = params[(ck << 8) | t];
    __syncthreads();

    const float z = fmaf((float)(g0 + lane), HH, ZMIN);
    float acc = 0.f, dacc = 0.f;
#pragma unroll 16
    for (int i = 0; i < 64; ++i) {
        const float4 p = ps[(wv << 6) + i];
        const float ap = fmaf(p.x, z, p.y);
        const float w  = __builtin_amdgcn_exp2f(fmaf(ap, z, p.z));
        acc += w;
        dacc = fmaf(w, fmaf(2.f, ap, -p.y), dacc);
    }
    __shared__ float2 part[256];
    part[t] = make_float2(acc, dacc);
    __syncthreads();
    if (t < 64) {
        const float2 p0 = part[t];
        const float2 p1 = part[t + 64];
        const float2 p2 = part[t + 128];
        const float2 p3 = part[t + 192];
        const float a  = (p0.x + p1.x) + (p2.x + p3.x);
        const float d  = (p0.y + p1.y) + (p2.y + p3.y);
        const float ag = fmaxf(a, 1e-30f);
        table[(ck << 10) | (g0 + t)] =
            make_float2(__builtin_amdgcn_logf(ag),
                        d * __builtin_amdgcn_rcpf(ag) * HH);
    }
}

// keval_nogather: native-layout coalesced eps float4 (4 k of one j), coalesced msd,
// Hermite nodes read directly from GLOBAL table (hot ~192KB, L1/L2-resident).
// No LDS staging, no transpose, no per-lane strided gather.
__global__ __launch_bounds__(256) void keval(const float* __restrict__ eps,
                                             const float2* __restrict__ msd,
                                             const float2* __restrict__ table,
                                             float* __restrict__ partial,
                                             unsigned* __restrict__ counter,
                                             float* __restrict__ out)
{
    const int t    = threadIdx.x;
    const int gidx = (blockIdx.x * 256 + t) << 2;     // flat (c,j,k), k fastest
    const int c    = gidx >> 18;                      // 8192*32 = 2^18 per chunk
    const int r18  = gidx & 262143;
    const int j    = r18 >> 5;
    const int k0   = r18 & 31;                        // multiple of 4
    const int row  = (c << 8) + (j >> 5);

    const float4 e4  = *(const float4*)(eps + gidx);                      // 16B coalesced
    const float* mp  = (const float*)(msd + ((row << 5) + k0));
    const float4 m01 = *(const float4*)(mp);                              // {mu0,sd0,mu1,sd1}
    const float4 m23 = *(const float4*)(mp + 4);                          // {mu2,sd2,mu3,sd3}

    const int ckb = (c << 5) + k0;

    float r = 0.f;
    {
        const float e[4]  = {e4.x, e4.y, e4.z, e4.w};
        const float mu[4] = {m01.x, m01.z, m23.x, m23.z};
        const float sd[4] = {m01.y, m01.w, m23.y, m23.w};
#pragma unroll
        for (int kk = 0; kk < 4; ++kk) {
            const float z  = fmaf(e[kk], sd[kk], mu[kk]);
            const float zc = fminf(fmaxf(z, -ZCLAMP), ZCLAMP);
            const float x  = fmaf(zc, INVH, 512.0f);      // (zc-ZMIN)*INVH
            const float fg = floorf(x);
            const float f  = x - fg;
            const int  ig  = (int)fg;                     // in [1,1022]
            const float2* __restrict__ tg = table + ((ckb + kk) << 10);
            const float2 n0 = tg[ig];
            const float2 n1 = tg[ig + 1];
            const float dl  = n1.x - n0.x;
            const float c2  = 3.f * dl - 2.f * n0.y - n1.y;
            const float c3  = n0.y + n1.y - 2.f * dl;
            const float L   = fmaf(f, fmaf(f, fmaf(f, c3, c2), n0.y), n0.x);
            r += fmaf(LN2, L, 0.5f * z * z);
        }
    }

    // deterministic block reduction
    for (int off = 32; off > 0; off >>= 1) r += __shfl_down(r, off, 64);
    __shared__ float wsum[4];
    if ((t & 63) == 0) wsum[t >> 6] = r;
    __syncthreads();

    __shared__ int isLast;
    if (t == 0) {
        partial[blockIdx.x] = (wsum[0] + wsum[1]) + (wsum[2] + wsum[3]);
        __threadfence();
        const unsigned old = atomicAdd(counter, 1u);
        isLast = (old == (unsigned)(NEV - 1));
    }
    __syncthreads();
    if (isLast) {
        __threadfence();
        double s = 0.0;
#pragma unroll
        for (int i = 0; i < NEV / 256; ++i) s += (double)partial[i * 256 + t];
        __shared__ double sd2[256];
        sd2[t] = s;
        __syncthreads();
        for (int off = 128; off > 0; off >>= 1) {
            if (t < off) sd2[t] += sd2[t + off];
            __syncthreads();
        }
        if (t == 0)
            out[0] = (float)(sd2[0] * (1.0 / (double)(NC * M))
                             - (double)D * 5.545177444479562);   // - D*ln(256)
    }
}

// ---- fallback (ws too small; not expected) ----
__global__ void kzero(unsigned* __restrict__ counter) { counter[0] = 0u; }

__global__ __launch_bounds__(256) void kfb(const float* __restrict__ eps,
                                           const float* __restrict__ mean,
                                           const float* __restrict__ logvar,
                                           float* __restrict__ partial,
                                           unsigned* __restrict__ counter,
                                           float* __restrict__ out)
{
    const int bid = blockIdx.x;
    const int ck  = bid >> 3;
    const int q   = bid & 7;
    const int c   = ck >> 5;
    const int k   = ck & (D - 1);
    const int j0  = q << 10;
    const int t   = threadIdx.x;

    __shared__ float4 prm[AGG];
    {
        const int row  = (c << 8) + t;
        const float mu = mean[row * D + k];
        const float lv = logvar[row * D + k];
        const float ev = __builtin_amdgcn_exp2f(-lv * LOG2E);
        prm[t] = make_float4(-0.5f * LOG2E * ev, LOG2E * mu * ev,
                             -0.5f * LOG2E * fmaf(mu * mu, ev, lv),
                             __builtin_amdgcn_exp2f(0.5f * LOG2E * lv));
    }
    __syncthreads();

    float zv[4], acc[4];
#pragma unroll
    for (int u = 0; u < 4; ++u) {
        const int j    = j0 + t + (u << 8);
        const float4 p = prm[j >> 5];
        const float mu = -0.5f * p.y * __builtin_amdgcn_rcpf(p.x);
        zv[u]  = fmaf(eps[(size_t)((c << 13) + j) * D + k], p.w, mu);
        acc[u] = 0.f;
    }
#pragma unroll 4
    for (int i = 0; i < AGG; ++i) {
        const float4 p = prm[i];
#pragma unroll
        for (int u = 0; u < 4; ++u)
            acc[u] += __builtin_amdgcn_exp2f(fmaf(fmaf(p.x, zv[u], p.y), zv[u], p.z));
    }
    float r = 0.f;
#pragma unroll
    for (int u = 0; u < 4; ++u)
        r += LN2 * __builtin_amdgcn_logf(acc[u]) + 0.5f * zv[u] * zv[u];

    for (int off = 32; off > 0; off >>= 1) r += __shfl_down(r, off, 64);
    __shared__ float wsum[4];
    if ((t & 63) == 0) wsum[t >> 6] = r;
    __syncthreads();
    __shared__ int isLast;
    if (t == 0) {
        partial[bid] = (wsum[0] + wsum[1]) + (wsum[2] + wsum[3]);
        __threadfence();
        const unsigned old = atomicAdd(counter, 1u);
        isLast = (old == (unsigned)(NEV - 1));
    }
    __syncthreads();
    if (isLast) {
        __threadfence();
        double s = 0.0;
#pragma unroll
        for (int i = 0; i < NEV / 256; ++i) s += (double)partial[i * 256 + t];
        __shared__ double sd2[256];
        sd2[t] = s;
        __syncthreads();
        for (int off = 128; off > 0; off >>= 1) {
            if (t < off) sd2[t] += sd2[t + off];
            __syncthreads();
        }
        if (t == 0)
            out[0] = (float)(sd2[0] * (1.0 / (double)(NC * M))
                             - (double)D * 5.545177444479562);
    }
}

extern "C" void kernel_launch(void* const* d_in, const int* in_sizes, int n_in,
                              void* d_out, int out_size, void* d_ws, size_t ws_size,
                              hipStream_t stream)
{
    const float* mean   = (const float*)d_in[0];
    const float* logvar = (const float*)d_in[1];
    const float* eps    = (const float*)d_in[2];
    float* out = (float*)d_out;

    unsigned* counter = (unsigned*)d_ws;
    float*    partial = (float*)((char*)d_ws + WS_PARTIAL);
    float4*   params  = (float4*)((char*)d_ws + WS_PARAMS);
    float2*   msd     = (float2*)((char*)d_ws + WS_MSD);
    float2*   table   = (float2*)((char*)d_ws + WS_TABLE);

    if (ws_size >= (size_t)WS_NEED) {
        ksetup<<<(B * D) / 256, 256, 0, stream>>>(mean, logvar, params, msd, counter);
        ktable<<<128 * 16, 256, 0, stream>>>(params, table);
        keval<<<NEV, 256, 0, stream>>>(eps, msd, table, partial, counter, out);
    } else {
        kzero<<<1, 64, 0, stream>>>(counter);
        kfb<<<NEV, 256, 0, stream>>>(eps, mean, logvar, partial, counter, out);
    }
}